// Round 4
// baseline (492.457 us; speedup 1.0000x reference)
//
#include <hip/hip_runtime.h>

// Problem dims (fixed)
#define BB 8
#define TT 1024
#define DD 1024
#define HH 16
#define AA 64
#define EE 262144

typedef unsigned short u16;
typedef unsigned int u32;
typedef short bf16x8 __attribute__((ext_vector_type(8)));
typedef float f32x4 __attribute__((ext_vector_type(4)));

__device__ __forceinline__ float bf2f(u16 u) {
    union { float f; u32 i; } c; c.i = ((u32)u) << 16; return c.f;
}
__device__ __forceinline__ u16 f2bf(float f) {
    union { float f; u32 i; } c; c.f = f;
    u32 x = c.i;
    return (u16)((x + 0x7FFFu + ((x >> 16) & 1u)) >> 16);
}

// async 16B global->LDS (per-lane gptr, wave-uniform LDS base; HW adds lane*16)
#define GLDS16(gp, lp)                                                        \
    __builtin_amdgcn_global_load_lds(                                         \
        (const __attribute__((address_space(1))) u32*)(const void*)(gp),      \
        (__attribute__((address_space(3))) u32*)(void*)(lp), 16, 0, 0)

#define MFMA(a, b, c) __builtin_amdgcn_mfma_f32_16x16x32_bf16((a), (b), (c), 0, 0, 0)

// ---------------------------------------------------------------------------
// mb init: mb[i] = mask ? -1e30 : 0   (8 elems/thread)
// ---------------------------------------------------------------------------
__global__ __launch_bounds__(256) void mbinit(const float* __restrict__ masks,
                                              float* __restrict__ mb) {
    size_t i = ((size_t)blockIdx.x * 256 + threadIdx.x) * 8;
    f32x4 a = *(const f32x4*)(masks + i);
    f32x4 b = *(const f32x4*)(masks + i + 4);
    f32x4 oa, ob;
#pragma unroll
    for (int j = 0; j < 4; j++) {
        oa[j] = (a[j] != 0.f) ? -1.0e30f : 0.f;
        ob[j] = (b[j] != 0.f) ? -1.0e30f : 0.f;
    }
    *(f32x4*)(mb + i) = oa;
    *(f32x4*)(mb + i + 4) = ob;
}

// ---------------------------------------------------------------------------
// scatter pass 1 — last edge index wins (numpy semantics)
// ---------------------------------------------------------------------------
__global__ __launch_bounds__(256) void scat_max(const int* __restrict__ ab,
                                                int* __restrict__ idx) {
    int e = blockIdx.x * 256 + threadIdx.x;
    const int* rec = ab + (size_t)e * 4;
    int b = rec[1], q = rec[2], k = rec[3];
    atomicMax(&idx[((((size_t)b << 10) + q) << 10) + k], e);
}

// scatter pass 2 — winner writes prescaled value into mb (skip masked cells)
__global__ __launch_bounds__(256) void scat_res(const int* __restrict__ ab,
                                                const int* __restrict__ idx,
                                                const float* __restrict__ be,
                                                const float* __restrict__ bsc,
                                                float* __restrict__ mb) {
    __shared__ float proj[32];
    int tid = threadIdx.x;
    if (tid < 32) {
        float s = 0.f;
        for (int a = 0; a < 64; a++) s += be[tid * 64 + a] * bsc[a];
        proj[tid] = s * 0.125f;  // fold 1/sqrt(A)
    }
    __syncthreads();
    int e = blockIdx.x * 256 + tid;
    const int* rec = ab + (size_t)e * 4;
    int et = rec[0], b = rec[1], q = rec[2], k = rec[3];
    size_t cell = ((((size_t)b << 10) + q) << 10) + k;
    if (idx[cell] == e && mb[cell] > -1.0e29f) mb[cell] = proj[et];
}

// ---------------------------------------------------------------------------
// transpose 4 f32 weight matrices (1024x1024) -> bf16 (N,K)
// ---------------------------------------------------------------------------
__global__ __launch_bounds__(256) void tr_w(const float* __restrict__ s0,
                                            const float* __restrict__ s1,
                                            const float* __restrict__ s2,
                                            const float* __restrict__ s3,
                                            u16* __restrict__ dstbase) {
    __shared__ u16 t[64 * 72];
    int tid = threadIdx.x;
    int z = blockIdx.z;
    const float* src = (z == 0) ? s0 : (z == 1) ? s1 : (z == 2) ? s2 : s3;
    u16* dst = dstbase + (size_t)z * 1024 * 1024;
    int row0 = blockIdx.y * 64, col0 = blockIdx.x * 64;
    int r = tid >> 2, c0 = (tid & 3) * 16;
    const float* sp = src + (size_t)(row0 + r) * 1024 + col0 + c0;
    f32x4 f0 = *(const f32x4*)(sp);
    f32x4 f1 = *(const f32x4*)(sp + 4);
    f32x4 f2_ = *(const f32x4*)(sp + 8);
    f32x4 f3 = *(const f32x4*)(sp + 12);
#pragma unroll
    for (int j = 0; j < 4; j++) {
        t[r * 72 + c0 + j] = f2bf(f0[j]);
        t[r * 72 + c0 + 4 + j] = f2bf(f1[j]);
        t[r * 72 + c0 + 8 + j] = f2bf(f2_[j]);
        t[r * 72 + c0 + 12 + j] = f2bf(f3[j]);
    }
    __syncthreads();
    bf16x8 o0, o1;
#pragma unroll
    for (int j = 0; j < 8; j++) o0[j] = (short)t[(c0 + j) * 72 + r];
#pragma unroll
    for (int j = 0; j < 8; j++) o1[j] = (short)t[(c0 + 8 + j) * 72 + r];
    *(bf16x8*)(dst + (size_t)(col0 + r) * 1024 + row0 + c0) = o0;
    *(bf16x8*)(dst + (size_t)(col0 + r) * 1024 + row0 + c0 + 8) = o1;
}

// ---------------------------------------------------------------------------
// GEMM: M=8192 N=1024 K=1024, 128x128 tile, BK=32.
// A: f32 (af32=1, converted in staging) or bf16 row-major (M,K).
// BT: bf16 (N,K), staged via global_load_lds w/ XOR(row>>1) chunk swizzle.
// mode 0: C f32 (M,N).  mode 1: C bf16 -> [B,H,T,A], scaled.
// ---------------------------------------------------------------------------
__global__ __launch_bounds__(256) void gemm2(const void* __restrict__ A,
                                             const u16* __restrict__ BT,
                                             void* __restrict__ C,
                                             int mode, int af32, float scale) {
    __shared__ u16 Asm[128 * 32];
    __shared__ u16 Bsm[128 * 32];
    int tid = threadIdx.x;
    int wave = tid >> 6, lane = tid & 63;
    int quad = lane >> 4, l16 = lane & 15;
    int wm = wave >> 1, wn = wave & 1;
    int mbase = blockIdx.y * 128, nbase = blockIdx.x * 128;
    f32x4 acc[4][4] = {};
    // A staging (VGPR path): 2 lanes/row, 16 elems each
    int srow = tid >> 1, scol = (tid & 1) * 16;
    int sA = (tid >> 2) & 3;                       // = (srow>>1)&3
    int p0 = ((((tid & 1) * 2) ^ sA)) * 8;         // physical chunk offsets (u16)
    int p1 = ((((tid & 1) * 2 + 1) ^ sA)) * 8;
    // B async mapping: wave covers 32 rows in 2 issues of 16 rows
    int brow = wave * 32 + (lane >> 2);
    int bch = ((lane & 3) ^ ((lane >> 3) & 3)) * 8;  // swizzled chunk (u16 offset)
    const u16* gB = BT + (size_t)(nbase + brow) * 1024 + bch;
    u16* lB = Bsm + wave * 32 * 32;
    int sw = (l16 >> 1) & 3;                       // frag-read swizzle
    const float* Af = (const float*)A;
    const u16* Ab = (const u16*)A;
    for (int k0 = 0; k0 < 1024; k0 += 32) {
        bf16x8 h0, h1;
        if (af32) {
            const float* ap = Af + (size_t)(mbase + srow) * 1024 + k0 + scol;
            f32x4 f0 = *(const f32x4*)(ap);
            f32x4 f1 = *(const f32x4*)(ap + 4);
            f32x4 f2_ = *(const f32x4*)(ap + 8);
            f32x4 f3 = *(const f32x4*)(ap + 12);
#pragma unroll
            for (int j = 0; j < 4; j++) {
                h0[j] = (short)f2bf(f0[j]); h0[4 + j] = (short)f2bf(f1[j]);
                h1[j] = (short)f2bf(f2_[j]); h1[4 + j] = (short)f2bf(f3[j]);
            }
        } else {
            const u16* ap = Ab + (size_t)(mbase + srow) * 1024 + k0 + scol;
            h0 = *(const bf16x8*)(ap);
            h1 = *(const bf16x8*)(ap + 8);
        }
        __syncthreads();  // all waves done reading prev-iter LDS
        GLDS16(gB + k0, lB);
        GLDS16(gB + k0 + 16 * 1024, lB + 16 * 32);
        *(bf16x8*)&Asm[srow * 32 + p0] = h0;
        *(bf16x8*)&Asm[srow * 32 + p1] = h1;
        __syncthreads();  // drains vmcnt (async LDS) + lgkm
        bf16x8 af[4], bfr[4];
#pragma unroll
        for (int mt = 0; mt < 4; mt++)
            af[mt] = *(const bf16x8*)&Asm[(wm * 64 + mt * 16 + l16) * 32 + (quad ^ sw) * 8];
#pragma unroll
        for (int nt = 0; nt < 4; nt++)
            bfr[nt] = *(const bf16x8*)&Bsm[(wn * 64 + nt * 16 + l16) * 32 + (quad ^ sw) * 8];
#pragma unroll
        for (int mt = 0; mt < 4; mt++)
#pragma unroll
            for (int nt = 0; nt < 4; nt++)
                acc[mt][nt] = MFMA(af[mt], bfr[nt], acc[mt][nt]);
    }
#pragma unroll
    for (int mt = 0; mt < 4; mt++)
#pragma unroll
        for (int nt = 0; nt < 4; nt++)
#pragma unroll
            for (int r = 0; r < 4; r++) {
                int gm = mbase + wm * 64 + mt * 16 + quad * 4 + r;
                int gn = nbase + wn * 64 + nt * 16 + l16;
                if (mode == 0) {
                    ((float*)C)[(size_t)gm * 1024 + gn] = acc[mt][nt][r];
                } else {
                    int b = gm >> 10, t = gm & 1023, h = gn >> 6, a = gn & 63;
                    ((u16*)C)[(((size_t)(b * 16 + h) * 1024) + t) * 64 + a] =
                        f2bf(acc[mt][nt][r] * scale);
                }
            }
}

// ---------------------------------------------------------------------------
// transpose v [B,H,T,A] -> vT [B,H,A,T]  (bf16)
// ---------------------------------------------------------------------------
__global__ __launch_bounds__(256) void tr_v(const u16* __restrict__ v,
                                            u16* __restrict__ vT) {
    __shared__ u16 t[64 * 72];
    int tid = threadIdx.x;
    int bh = blockIdx.y;
    int t0 = blockIdx.x * 64;
    int r = tid >> 2, c0 = (tid & 3) * 16;
    const u16* src = v + (size_t)bh * 1024 * 64;
    u16* dst = vT + (size_t)bh * 64 * 1024;
    bf16x8 v0 = *(const bf16x8*)(src + (size_t)(t0 + r) * 64 + c0);
    bf16x8 v1 = *(const bf16x8*)(src + (size_t)(t0 + r) * 64 + c0 + 8);
    *(bf16x8*)&t[r * 72 + c0] = v0;
    *(bf16x8*)&t[r * 72 + c0 + 8] = v1;
    __syncthreads();
    bf16x8 o0, o1;
#pragma unroll
    for (int j = 0; j < 8; j++) o0[j] = (short)t[(c0 + j) * 72 + r];
#pragma unroll
    for (int j = 0; j < 8; j++) o1[j] = (short)t[(c0 + 8 + j) * 72 + r];
    *(bf16x8*)(dst + (size_t)r * 1024 + t0 + c0) = o0;
    *(bf16x8*)(dst + (size_t)r * 1024 + t0 + c0 + 8) = o1;
}

// ---------------------------------------------------------------------------
// ksum[b,h,t] = sum_a k[b,h,t,a]
// ---------------------------------------------------------------------------
__global__ __launch_bounds__(256) void ksumk(const u16* __restrict__ k,
                                             float* __restrict__ ks) {
    int i = blockIdx.x * 256 + threadIdx.x;
    const u16* kp = k + (size_t)i * 64;
    float s = 0.f;
#pragma unroll
    for (int c = 0; c < 64; c += 8) {
        bf16x8 v = *(const bf16x8*)(kp + c);
#pragma unroll
        for (int j = 0; j < 8; j++) s += bf2f((u16)v[j]);
    }
    ks[i] = s;
}

// ---------------------------------------------------------------------------
// attn v2: S^T = K·Q^T (C-layout: row=k, col=q), fixed-offset softmax (-20
// folded into S-accumulator init), fused mask+bias buffer mb, P^T->Psm[q][k]
// packed b32 writes (same-wave round trip), PV = P·V with V^T-layout LDS.
// ---------------------------------------------------------------------------
__global__ __launch_bounds__(256) void attn2(const u16* __restrict__ qbuf,
                                             const u16* __restrict__ kbuf,
                                             const u16* __restrict__ vT,
                                             const float* __restrict__ ksum,
                                             const float* __restrict__ mb,
                                             u16* __restrict__ ctx) {
    __shared__ u16 Ksm[64 * 72];
    __shared__ u16 Vsm[64 * 72];
    __shared__ u16 Psm[4 * 16 * 72];
    __shared__ float sksm[64];
    __shared__ float lsm[64];
    int tid = threadIdx.x;
    int wave = tid >> 6, lane = tid & 63;
    int quad = lane >> 4, l16 = lane & 15;
    int qb = blockIdx.x, h = blockIdx.y, b = blockIdx.z;
    int bh = b * 16 + h;
    const u16* qp = qbuf + (size_t)bh * 65536;
    const u16* kp = kbuf + (size_t)bh * 65536;
    const u16* vp = vT + (size_t)bh * 65536;
    const float* ksp = ksum + (size_t)bh * 1024;
    int q0 = qb * 64 + wave * 16;
    const float* mbp = mb + ((size_t)b * 1024 + (q0 + l16)) * 1024;

    bf16x8 qf0 = *(const bf16x8*)(qp + (size_t)(q0 + l16) * 64 + quad * 8);
    bf16x8 qf1 = *(const bf16x8*)(qp + (size_t)(q0 + l16) * 64 + 32 + quad * 8);

    f32x4 oacc[4] = {};
    float lsum = 0.f;
    int srow = tid >> 2, sc0 = (tid & 3) * 16;
    u16* pw = &Psm[wave * 16 * 72];

    for (int kb = 0; kb < 1024; kb += 64) {
        bf16x8 k0 = *(const bf16x8*)(kp + (size_t)(kb + srow) * 64 + sc0);
        bf16x8 k1 = *(const bf16x8*)(kp + (size_t)(kb + srow) * 64 + sc0 + 8);
        bf16x8 v0 = *(const bf16x8*)(vp + (size_t)srow * 1024 + kb + sc0);
        bf16x8 v1 = *(const bf16x8*)(vp + (size_t)srow * 1024 + kb + sc0 + 8);
        // mask+bias vector loads (global, independent of LDS barriers)
        f32x4 mbv[4];
#pragma unroll
        for (int nt = 0; nt < 4; nt++)
            mbv[nt] = *(const f32x4*)(mbp + kb + nt * 16 + quad * 4);
        __syncthreads();
        *(bf16x8*)&Ksm[srow * 72 + sc0] = k0;
        *(bf16x8*)&Ksm[srow * 72 + sc0 + 8] = k1;
        *(bf16x8*)&Vsm[srow * 72 + sc0] = v0;
        *(bf16x8*)&Vsm[srow * 72 + sc0 + 8] = v1;
        if (tid < 64) sksm[tid] = ksp[kb + tid];
        __syncthreads();

        // S^T = K·Q^T, accumulator pre-biased with softmax offset -20
        f32x4 sacc[4];
#pragma unroll
        for (int nt = 0; nt < 4; nt++) sacc[nt] = f32x4{-20.f, -20.f, -20.f, -20.f};
#pragma unroll
        for (int nt = 0; nt < 4; nt++) {
            bf16x8 kf0 = *(const bf16x8*)&Ksm[(nt * 16 + l16) * 72 + quad * 8];
            bf16x8 kf1 = *(const bf16x8*)&Ksm[(nt * 16 + l16) * 72 + 32 + quad * 8];
            sacc[nt] = MFMA(kf0, qf0, sacc[nt]);
            sacc[nt] = MFMA(kf1, qf1, sacc[nt]);
        }

        // softmax weights: p = unmasked ? exp(s + bias*ksum - 20) : 0
#pragma unroll
        for (int nt = 0; nt < 4; nt++) {
            f32x4 k4 = *(const f32x4*)&sksm[nt * 16 + quad * 4];
            float p[4];
#pragma unroll
            for (int r = 0; r < 4; r++) {
                float e = __expf(sacc[nt][r] + mbv[nt][r] * k4[r]);
                p[r] = (mbv[nt][r] > -1.0e29f) ? e : 0.f;
                lsum += p[r];
            }
            u32 w0 = (u32)f2bf(p[0]) | ((u32)f2bf(p[1]) << 16);
            u32 w1 = (u32)f2bf(p[2]) | ((u32)f2bf(p[3]) << 16);
            *(u32*)&pw[l16 * 72 + nt * 16 + quad * 4] = w0;
            *(u32*)&pw[l16 * 72 + nt * 16 + quad * 4 + 2] = w1;
        }

        // PV: O += P·V  (P from same-wave LDS region; compiler orders DS ops)
#pragma unroll
        for (int s = 0; s < 2; s++) {
            bf16x8 pf = *(const bf16x8*)&pw[l16 * 72 + s * 32 + quad * 8];
#pragma unroll
            for (int at = 0; at < 4; at++) {
                bf16x8 vf = *(const bf16x8*)&Vsm[(at * 16 + l16) * 72 + s * 32 + quad * 8];
                oacc[at] = MFMA(pf, vf, oacc[at]);
            }
        }
    }

    // row-sum reduce across quads (lane l16 holds partial for q=q0+l16)
    lsum += __shfl_xor(lsum, 16);
    lsum += __shfl_xor(lsum, 32);
    if (lane < 16) lsm[wave * 16 + lane] = lsum;
    __syncthreads();

    // epilogue: ctx[b,q,h,a], coalesced over l16 = a
#pragma unroll
    for (int r = 0; r < 4; r++) {
        float linv = 1.0f / lsm[wave * 16 + quad * 4 + r];
        int q = q0 + quad * 4 + r;
#pragma unroll
        for (int at = 0; at < 4; at++) {
            ctx[(((size_t)b * 1024 + q) * 16 + h) * 64 + at * 16 + l16] =
                f2bf(oacc[at][r] * linv);
        }
    }
}

// ---------------------------------------------------------------------------
extern "C" void kernel_launch(void* const* d_in, const int* in_sizes, int n_in,
                              void* d_out, int out_size, void* d_ws, size_t ws_size,
                              hipStream_t stream) {
    const float* states = (const float*)d_in[0];
    const float* key_states = (const float*)d_in[1];
    const float* masks = (const float*)d_in[2];
    const int* abias = (const int*)d_in[3];
    const float* Wq = (const float*)d_in[4];
    const float* Wk = (const float*)d_in[5];
    const float* Wv = (const float*)d_in[6];
    const float* Wout = (const float*)d_in[7];
    const float* be = (const float*)d_in[8];
    const float* bsc = (const float*)d_in[9];

    char* ws = (char*)d_ws;
    size_t off = 0;
    auto alloc = [&](size_t n) { void* p = ws + off; off += (n + 255) & ~(size_t)255; return p; };
    u16* wT = (u16*)alloc(4ull * 1024 * 1024 * 2);          // weights^T bf16 (8 MB)
    u16* qb_ = (u16*)alloc((size_t)BB * HH * TT * AA * 2);  // q [B,H,T,A] (16 MB)
    u16* kb_ = (u16*)alloc((size_t)BB * HH * TT * AA * 2);  // k [B,H,T,A] (16 MB)
    u16* vb_ = (u16*)alloc((size_t)BB * HH * TT * AA * 2);  // v [B,H,T,A] (16 MB)
    u16* vT_ = (u16*)alloc((size_t)BB * HH * AA * TT * 2);  // vT [B,H,A,T] (16 MB)
    float* ks_ = (float*)alloc((size_t)BB * HH * TT * 4);   // ksum (0.5 MB)
    float* mb_ = (float*)alloc((size_t)BB * TT * TT * 4);   // fused mask+bias (32 MB)

    u16* wqT = wT;
    u16* wkT = wT + 1048576;
    u16* wvT = wT + 2097152;
    u16* woT = wT + 3145728;
    int* idx_ = (int*)qb_;   // 32 MB over qb_+kb_ (dead until projections)
    u16* ctx_ = vb_;         // vb_ dead after tr_v

    // 1) scatter-idx init + fused mask/bias init
    hipMemsetAsync(idx_, 0xFF, (size_t)BB * TT * TT * 4, stream);
    mbinit<<<dim3(4096), 256, 0, stream>>>(masks, mb_);
    // 2) deterministic scatter into mb (last-edge-wins, masked cells excluded)
    scat_max<<<dim3(EE / 256), 256, 0, stream>>>(abias, idx_);
    scat_res<<<dim3(EE / 256), 256, 0, stream>>>(abias, idx_, be, bsc, mb_);
    // 3) weights f32 -> bf16 transposed
    tr_w<<<dim3(16, 16, 4), 256, 0, stream>>>(Wq, Wk, Wv, Wout, wT);
    // 4) projections (A = f32 activations, converted in staging; q pre-scaled)
    gemm2<<<dim3(8, 64), 256, 0, stream>>>(states, wqT, qb_, 1, 1, 0.125f);
    gemm2<<<dim3(8, 64), 256, 0, stream>>>(key_states, wkT, kb_, 1, 1, 1.0f);
    gemm2<<<dim3(8, 64), 256, 0, stream>>>(key_states, wvT, vb_, 1, 1, 1.0f);
    // 5) v transpose
    tr_v<<<dim3(16, 128), 256, 0, stream>>>(vb_, vT_);
    // 6) ksum
    ksumk<<<dim3(512), 256, 0, stream>>>(kb_, ks_);
    // 7) attention
    attn2<<<dim3(16, 16, 8), 256, 0, stream>>>(qb_, kb_, vT_, ks_, mb_, ctx_);
    // 8) output projection -> d_out (f32)
    gemm2<<<dim3(8, 64), 256, 0, stream>>>(ctx_, woT, d_out, 0, 0, 1.0f);
}

// Round 5
// 439.874 us; speedup vs baseline: 1.1195x; 1.1195x over previous
//
#include <hip/hip_runtime.h>
#include <hip/hip_bf16.h>

// Problem dims (fixed)
#define BB 8
#define TT 1024
#define DD 1024
#define HH 16
#define AA 64
#define EE 262144

typedef unsigned short u16;
typedef unsigned int u32;
typedef short bf16x8 __attribute__((ext_vector_type(8)));
typedef float f32x4 __attribute__((ext_vector_type(4)));

__device__ __forceinline__ float bf2f(u16 u) {
    union { float f; u32 i; } c; c.i = ((u32)u) << 16; return c.f;
}
__device__ __forceinline__ u16 f2bf(float f) {
    union { float f; u32 i; } c; c.f = f;
    u32 x = c.i;
    return (u16)((x + 0x7FFFu + ((x >> 16) & 1u)) >> 16);
}
// packed 2xf32 -> 2xbf16 (v_cvt_pk_bf16_f32 on gfx950)
__device__ __forceinline__ u32 pack2bf(float a, float b) {
    union { __hip_bfloat162 h; u32 u; } c;
    c.h = __float22bfloat162_rn(float2{a, b});
    return c.u;
}

// async 16B global->LDS (per-lane gptr, wave-uniform LDS base; HW adds lane*16)
#define GLDS16(gp, lp)                                                        \
    __builtin_amdgcn_global_load_lds(                                         \
        (const __attribute__((address_space(1))) u32*)(const void*)(gp),      \
        (__attribute__((address_space(3))) u32*)(void*)(lp), 16, 0, 0)

#define MFMA(a, b, c) __builtin_amdgcn_mfma_f32_16x16x32_bf16((a), (b), (c), 0, 0, 0)

// ---------------------------------------------------------------------------
// cvt: elementwise f32 -> bf16 (8 elems/thread), BW-bound
// ---------------------------------------------------------------------------
__global__ __launch_bounds__(256) void cvt(const float* __restrict__ src,
                                           u16* __restrict__ dst) {
    size_t i = ((size_t)blockIdx.x * 256 + threadIdx.x) * 8;
    f32x4 a = *(const f32x4*)(src + i);
    f32x4 b = *(const f32x4*)(src + i + 4);
    u32 o[4];
    o[0] = pack2bf(a[0], a[1]);
    o[1] = pack2bf(a[2], a[3]);
    o[2] = pack2bf(b[0], b[1]);
    o[3] = pack2bf(b[2], b[3]);
    *(bf16x8*)(dst + i) = *(bf16x8*)o;
}

// ---------------------------------------------------------------------------
// mb init: mb[i] = mask ? -1e30 : 0
// ---------------------------------------------------------------------------
__global__ __launch_bounds__(256) void mbinit(const float* __restrict__ masks,
                                              float* __restrict__ mb) {
    size_t i = ((size_t)blockIdx.x * 256 + threadIdx.x) * 8;
    f32x4 a = *(const f32x4*)(masks + i);
    f32x4 b = *(const f32x4*)(masks + i + 4);
    f32x4 oa, ob;
#pragma unroll
    for (int j = 0; j < 4; j++) {
        oa[j] = (a[j] != 0.f) ? -1.0e30f : 0.f;
        ob[j] = (b[j] != 0.f) ? -1.0e30f : 0.f;
    }
    *(f32x4*)(mb + i) = oa;
    *(f32x4*)(mb + i + 4) = ob;
}

// ---------------------------------------------------------------------------
// scatter pass 1 — last edge index wins (numpy semantics)
// ---------------------------------------------------------------------------
__global__ __launch_bounds__(256) void scat_max(const int* __restrict__ ab,
                                                int* __restrict__ idx) {
    int e = blockIdx.x * 256 + threadIdx.x;
    const int* rec = ab + (size_t)e * 4;
    int b = rec[1], q = rec[2], k = rec[3];
    atomicMax(&idx[((((size_t)b << 10) + q) << 10) + k], e);
}

// scatter pass 2 — winner writes prescaled value into mb (skip masked cells)
__global__ __launch_bounds__(256) void scat_res(const int* __restrict__ ab,
                                                const int* __restrict__ idx,
                                                const float* __restrict__ be,
                                                const float* __restrict__ bsc,
                                                float* __restrict__ mb) {
    __shared__ float proj[32];
    int tid = threadIdx.x;
    if (tid < 32) {
        float s = 0.f;
        for (int a = 0; a < 64; a++) s += be[tid * 64 + a] * bsc[a];
        proj[tid] = s * 0.125f;  // fold 1/sqrt(A)
    }
    __syncthreads();
    int e = blockIdx.x * 256 + tid;
    const int* rec = ab + (size_t)e * 4;
    int et = rec[0], b = rec[1], q = rec[2], k = rec[3];
    size_t cell = ((((size_t)b << 10) + q) << 10) + k;
    if (idx[cell] == e && mb[cell] > -1.0e29f) mb[cell] = proj[et];
}

// ---------------------------------------------------------------------------
// transpose 4 f32 weight matrices (1024x1024) -> bf16 (N,K)
// ---------------------------------------------------------------------------
__global__ __launch_bounds__(256) void tr_w(const float* __restrict__ s0,
                                            const float* __restrict__ s1,
                                            const float* __restrict__ s2,
                                            const float* __restrict__ s3,
                                            u16* __restrict__ dstbase) {
    __shared__ u16 t[64 * 72];
    int tid = threadIdx.x;
    int z = blockIdx.z;
    const float* src = (z == 0) ? s0 : (z == 1) ? s1 : (z == 2) ? s2 : s3;
    u16* dst = dstbase + (size_t)z * 1024 * 1024;
    int row0 = blockIdx.y * 64, col0 = blockIdx.x * 64;
    int r = tid >> 2, c0 = (tid & 3) * 16;
    const float* sp = src + (size_t)(row0 + r) * 1024 + col0 + c0;
    f32x4 f0 = *(const f32x4*)(sp);
    f32x4 f1 = *(const f32x4*)(sp + 4);
    f32x4 f2_ = *(const f32x4*)(sp + 8);
    f32x4 f3 = *(const f32x4*)(sp + 12);
#pragma unroll
    for (int j = 0; j < 4; j++) {
        t[r * 72 + c0 + j] = f2bf(f0[j]);
        t[r * 72 + c0 + 4 + j] = f2bf(f1[j]);
        t[r * 72 + c0 + 8 + j] = f2bf(f2_[j]);
        t[r * 72 + c0 + 12 + j] = f2bf(f3[j]);
    }
    __syncthreads();
    bf16x8 o0, o1;
#pragma unroll
    for (int j = 0; j < 8; j++) o0[j] = (short)t[(c0 + j) * 72 + r];
#pragma unroll
    for (int j = 0; j < 8; j++) o1[j] = (short)t[(c0 + 8 + j) * 72 + r];
    *(bf16x8*)(dst + (size_t)(col0 + r) * 1024 + row0 + c0) = o0;
    *(bf16x8*)(dst + (size_t)(col0 + r) * 1024 + row0 + c0 + 8) = o1;
}

// ---------------------------------------------------------------------------
// gemm3: m97-style. M=8192 N=1024 K=1024, 128x128 tile, BK=32.
// A bf16 (M,K), BT bf16 (N,K). Both staged via global_load_lds width=16,
// unpadded LDS [128][32] u16, 2-barrier K-loop.
// mode 0: C f32 (M,N).  mode 1: C bf16 -> [B,H,T,A], scaled.
// ---------------------------------------------------------------------------
__global__ __launch_bounds__(256) void gemm3(const u16* __restrict__ A,
                                             const u16* __restrict__ BT,
                                             void* __restrict__ C,
                                             int mode, float scale) {
    __shared__ u16 Asm[128 * 32];
    __shared__ u16 Bsm[128 * 32];
    int tid = threadIdx.x;
    int wave = tid >> 6, lane = tid & 63;
    int quad = lane >> 4, l16 = lane & 15;
    int wm = wave >> 1, wn = wave & 1;
    int mbase = blockIdx.y * 128, nbase = blockIdx.x * 128;
    f32x4 acc[4][4] = {};
    // staging: wave w covers rows w*32..w*32+31 in two 16-row issues;
    // lane i -> row w*32 + j*16 + (i>>2), 16B chunk (i&3)  (LDS-linear order)
    int srow = wave * 32 + (lane >> 2);
    int scol = (lane & 3) * 8;
    const u16* gA = A + (size_t)(mbase + srow) * 1024 + scol;
    const u16* gB = BT + (size_t)(nbase + srow) * 1024 + scol;
    u16* lA = Asm + wave * 32 * 32;
    u16* lB = Bsm + wave * 32 * 32;
    for (int k0 = 0; k0 < 1024; k0 += 32) {
        __syncthreads();  // prior-iter ds_reads done
        GLDS16(gA + k0, lA);
        GLDS16(gA + k0 + 16 * 1024, lA + 16 * 32);
        GLDS16(gB + k0, lB);
        GLDS16(gB + k0 + 16 * 1024, lB + 16 * 32);
        __syncthreads();  // drains vmcnt (async LDS writes visible)
        bf16x8 af[4], bfr[4];
#pragma unroll
        for (int mt = 0; mt < 4; mt++)
            af[mt] = *(const bf16x8*)&Asm[(wm * 64 + mt * 16 + l16) * 32 + quad * 8];
#pragma unroll
        for (int nt = 0; nt < 4; nt++)
            bfr[nt] = *(const bf16x8*)&Bsm[(wn * 64 + nt * 16 + l16) * 32 + quad * 8];
#pragma unroll
        for (int mt = 0; mt < 4; mt++)
#pragma unroll
            for (int nt = 0; nt < 4; nt++)
                acc[mt][nt] = MFMA(af[mt], bfr[nt], acc[mt][nt]);
    }
#pragma unroll
    for (int mt = 0; mt < 4; mt++)
#pragma unroll
        for (int nt = 0; nt < 4; nt++)
#pragma unroll
            for (int r = 0; r < 4; r++) {
                int gm = mbase + wm * 64 + mt * 16 + quad * 4 + r;
                int gn = nbase + wn * 64 + nt * 16 + l16;
                if (mode == 0) {
                    ((float*)C)[(size_t)gm * 1024 + gn] = acc[mt][nt][r];
                } else {
                    int b = gm >> 10, t = gm & 1023, h = gn >> 6, a = gn & 63;
                    ((u16*)C)[(((size_t)(b * 16 + h) * 1024) + t) * 64 + a] =
                        f2bf(acc[mt][nt][r] * scale);
                }
            }
}

// ---------------------------------------------------------------------------
// transpose v [B,H,T,A] -> vT [B,H,A,T]  (bf16)
// ---------------------------------------------------------------------------
__global__ __launch_bounds__(256) void tr_v(const u16* __restrict__ v,
                                            u16* __restrict__ vT) {
    __shared__ u16 t[64 * 72];
    int tid = threadIdx.x;
    int bh = blockIdx.y;
    int t0 = blockIdx.x * 64;
    int r = tid >> 2, c0 = (tid & 3) * 16;
    const u16* src = v + (size_t)bh * 1024 * 64;
    u16* dst = vT + (size_t)bh * 64 * 1024;
    bf16x8 v0 = *(const bf16x8*)(src + (size_t)(t0 + r) * 64 + c0);
    bf16x8 v1 = *(const bf16x8*)(src + (size_t)(t0 + r) * 64 + c0 + 8);
    *(bf16x8*)&t[r * 72 + c0] = v0;
    *(bf16x8*)&t[r * 72 + c0 + 8] = v1;
    __syncthreads();
    bf16x8 o0, o1;
#pragma unroll
    for (int j = 0; j < 8; j++) o0[j] = (short)t[(c0 + j) * 72 + r];
#pragma unroll
    for (int j = 0; j < 8; j++) o1[j] = (short)t[(c0 + 8 + j) * 72 + r];
    *(bf16x8*)(dst + (size_t)r * 1024 + t0 + c0) = o0;
    *(bf16x8*)(dst + (size_t)r * 1024 + t0 + c0 + 8) = o1;
}

// ---------------------------------------------------------------------------
// ksum[b,h,t] = sum_a k[b,h,t,a]
// ---------------------------------------------------------------------------
__global__ __launch_bounds__(256) void ksumk(const u16* __restrict__ k,
                                             float* __restrict__ ks) {
    int i = blockIdx.x * 256 + threadIdx.x;
    const u16* kp = k + (size_t)i * 64;
    float s = 0.f;
#pragma unroll
    for (int c = 0; c < 64; c += 8) {
        bf16x8 v = *(const bf16x8*)(kp + c);
#pragma unroll
        for (int j = 0; j < 8; j++) s += bf2f((u16)v[j]);
    }
    ks[i] = s;
}

// ---------------------------------------------------------------------------
// attn2: S^T = K·Q^T (C-layout row=k col=q), fixed-offset softmax (-20 in
// accumulator init), fused mask+bias mb, packed-bf16 P write, PV = P·V.
// ---------------------------------------------------------------------------
__global__ __launch_bounds__(256) void attn2(const u16* __restrict__ qbuf,
                                             const u16* __restrict__ kbuf,
                                             const u16* __restrict__ vT,
                                             const float* __restrict__ ksum,
                                             const float* __restrict__ mb,
                                             u16* __restrict__ ctx) {
    __shared__ u16 Ksm[64 * 72];
    __shared__ u16 Vsm[64 * 72];
    __shared__ u16 Psm[4 * 16 * 72];
    __shared__ float sksm[64];
    __shared__ float lsm[64];
    int tid = threadIdx.x;
    int wave = tid >> 6, lane = tid & 63;
    int quad = lane >> 4, l16 = lane & 15;
    int qb = blockIdx.x, h = blockIdx.y, b = blockIdx.z;
    int bh = b * 16 + h;
    const u16* qp = qbuf + (size_t)bh * 65536;
    const u16* kp = kbuf + (size_t)bh * 65536;
    const u16* vp = vT + (size_t)bh * 65536;
    const float* ksp = ksum + (size_t)bh * 1024;
    int q0 = qb * 64 + wave * 16;
    const float* mbp = mb + ((size_t)b * 1024 + (q0 + l16)) * 1024;

    bf16x8 qf0 = *(const bf16x8*)(qp + (size_t)(q0 + l16) * 64 + quad * 8);
    bf16x8 qf1 = *(const bf16x8*)(qp + (size_t)(q0 + l16) * 64 + 32 + quad * 8);

    f32x4 oacc[4] = {};
    float lsum = 0.f;
    int srow = tid >> 2, sc0 = (tid & 3) * 16;
    u16* pw = &Psm[wave * 16 * 72];

    for (int kb = 0; kb < 1024; kb += 64) {
        bf16x8 k0 = *(const bf16x8*)(kp + (size_t)(kb + srow) * 64 + sc0);
        bf16x8 k1 = *(const bf16x8*)(kp + (size_t)(kb + srow) * 64 + sc0 + 8);
        bf16x8 v0 = *(const bf16x8*)(vp + (size_t)srow * 1024 + kb + sc0);
        bf16x8 v1 = *(const bf16x8*)(vp + (size_t)srow * 1024 + kb + sc0 + 8);
        f32x4 mbv[4];
#pragma unroll
        for (int nt = 0; nt < 4; nt++)
            mbv[nt] = *(const f32x4*)(mbp + kb + nt * 16 + quad * 4);
        __syncthreads();
        *(bf16x8*)&Ksm[srow * 72 + sc0] = k0;
        *(bf16x8*)&Ksm[srow * 72 + sc0 + 8] = k1;
        *(bf16x8*)&Vsm[srow * 72 + sc0] = v0;
        *(bf16x8*)&Vsm[srow * 72 + sc0 + 8] = v1;
        if (tid < 64) sksm[tid] = ksp[kb + tid];
        __syncthreads();

        // S^T = K·Q^T, accumulator pre-biased with softmax offset -20
        f32x4 sacc[4];
#pragma unroll
        for (int nt = 0; nt < 4; nt++) sacc[nt] = f32x4{-20.f, -20.f, -20.f, -20.f};
#pragma unroll
        for (int nt = 0; nt < 4; nt++) {
            bf16x8 kf0 = *(const bf16x8*)&Ksm[(nt * 16 + l16) * 72 + quad * 8];
            bf16x8 kf1 = *(const bf16x8*)&Ksm[(nt * 16 + l16) * 72 + 32 + quad * 8];
            sacc[nt] = MFMA(kf0, qf0, sacc[nt]);
            sacc[nt] = MFMA(kf1, qf1, sacc[nt]);
        }

        // p = unmasked ? exp(s + bias*ksum - 20) : 0 ; packed bf16 write
#pragma unroll
        for (int nt = 0; nt < 4; nt++) {
            f32x4 k4 = *(const f32x4*)&sksm[nt * 16 + quad * 4];
            float p[4];
#pragma unroll
            for (int r = 0; r < 4; r++) {
                float e = __expf(sacc[nt][r] + mbv[nt][r] * k4[r]);
                p[r] = (mbv[nt][r] > -1.0e29f) ? e : 0.f;
                lsum += p[r];
            }
            *(u32*)&pw[l16 * 72 + nt * 16 + quad * 4] = pack2bf(p[0], p[1]);
            *(u32*)&pw[l16 * 72 + nt * 16 + quad * 4 + 2] = pack2bf(p[2], p[3]);
        }

        // PV: O += P·V  (same-wave LDS round trip; compiler orders DS ops)
#pragma unroll
        for (int s = 0; s < 2; s++) {
            bf16x8 pf = *(const bf16x8*)&pw[l16 * 72 + s * 32 + quad * 8];
#pragma unroll
            for (int at = 0; at < 4; at++) {
                bf16x8 vf = *(const bf16x8*)&Vsm[(at * 16 + l16) * 72 + s * 32 + quad * 8];
                oacc[at] = MFMA(pf, vf, oacc[at]);
            }
        }
    }

    lsum += __shfl_xor(lsum, 16);
    lsum += __shfl_xor(lsum, 32);
    if (lane < 16) lsm[wave * 16 + lane] = lsum;
    __syncthreads();

#pragma unroll
    for (int r = 0; r < 4; r++) {
        float linv = 1.0f / lsm[wave * 16 + quad * 4 + r];
        int q = q0 + quad * 4 + r;
#pragma unroll
        for (int at = 0; at < 4; at++) {
            ctx[(((size_t)b * 1024 + q) * 16 + h) * 64 + at * 16 + l16] =
                f2bf(oacc[at][r] * linv);
        }
    }
}

// ---------------------------------------------------------------------------
extern "C" void kernel_launch(void* const* d_in, const int* in_sizes, int n_in,
                              void* d_out, int out_size, void* d_ws, size_t ws_size,
                              hipStream_t stream) {
    const float* states = (const float*)d_in[0];
    const float* key_states = (const float*)d_in[1];
    const float* masks = (const float*)d_in[2];
    const int* abias = (const int*)d_in[3];
    const float* Wq = (const float*)d_in[4];
    const float* Wk = (const float*)d_in[5];
    const float* Wv = (const float*)d_in[6];
    const float* Wout = (const float*)d_in[7];
    const float* be = (const float*)d_in[8];
    const float* bsc = (const float*)d_in[9];

    char* ws = (char*)d_ws;
    size_t off = 0;
    auto alloc = [&](size_t n) { void* p = ws + off; off += (n + 255) & ~(size_t)255; return p; };
    u16* wT = (u16*)alloc(4ull * 1024 * 1024 * 2);          // weights^T bf16 (8 MB)
    u16* sbf = (u16*)alloc((size_t)BB * TT * DD * 2);       // states bf16 (16 MB)
    u16* kbf = (u16*)alloc((size_t)BB * TT * DD * 2);       // key_states bf16 (16 MB)
    u16* qb_ = (u16*)alloc((size_t)BB * HH * TT * AA * 2);  // q [B,H,T,A] (16 MB)
    u16* kb_ = (u16*)alloc((size_t)BB * HH * TT * AA * 2);  // k [B,H,T,A] (16 MB)
    u16* vb_ = (u16*)alloc((size_t)BB * HH * TT * AA * 2);  // v [B,H,T,A] (16 MB)
    u16* vT_ = (u16*)alloc((size_t)BB * HH * AA * TT * 2);  // vT [B,H,A,T] (16 MB)
    float* ks_ = (float*)alloc((size_t)BB * HH * TT * 4);   // ksum (0.5 MB)
    float* mb_ = (float*)alloc((size_t)BB * TT * TT * 4);   // fused mask+bias (32 MB)

    u16* wqT = wT;
    u16* wkT = wT + 1048576;
    u16* wvT = wT + 2097152;
    u16* woT = wT + 3145728;
    int* idx_ = (int*)qb_;   // 32 MB over qb_+kb_ (dead until projections)
    u16* ctx_ = vb_;         // vb_ dead after tr_v

    // 1) scatter-idx init + fused mask/bias init
    hipMemsetAsync(idx_, 0xFF, (size_t)BB * TT * TT * 4, stream);
    mbinit<<<dim3(4096), 256, 0, stream>>>(masks, mb_);
    // 2) deterministic scatter into mb (last-edge-wins, masked cells excluded)
    scat_max<<<dim3(EE / 256), 256, 0, stream>>>(abias, idx_);
    scat_res<<<dim3(EE / 256), 256, 0, stream>>>(abias, idx_, be, bsc, mb_);
    // 3) weights f32 -> bf16 transposed
    tr_w<<<dim3(16, 16, 4), 256, 0, stream>>>(Wq, Wk, Wv, Wout, wT);
    // 4) activations f32 -> bf16 (BW-bound, keeps GEMM staging VALU-free)
    cvt<<<dim3(4096), 256, 0, stream>>>(states, sbf);
    cvt<<<dim3(4096), 256, 0, stream>>>(key_states, kbf);
    // 5) projections (q pre-scaled by 1/sqrt(A))
    gemm3<<<dim3(8, 64), 256, 0, stream>>>(sbf, wqT, qb_, 1, 0.125f);
    gemm3<<<dim3(8, 64), 256, 0, stream>>>(kbf, wkT, kb_, 1, 1.0f);
    gemm3<<<dim3(8, 64), 256, 0, stream>>>(kbf, wvT, vb_, 1, 1.0f);
    // 6) v transpose
    tr_v<<<dim3(16, 128), 256, 0, stream>>>(vb_, vT_);
    // 7) ksum
    ksumk<<<dim3(512), 256, 0, stream>>>(kb_, ks_);
    // 8) attention
    attn2<<<dim3(16, 16, 8), 256, 0, stream>>>(qb_, kb_, vT_, ks_, mb_, ctx_);
    // 9) output projection -> d_out (f32)
    gemm3<<<dim3(8, 64), 256, 0, stream>>>(ctx_, woT, d_out, 0, 1.0f);
}

// Round 6
// 410.885 us; speedup vs baseline: 1.1985x; 1.0706x over previous
//
#include <hip/hip_runtime.h>
#include <hip/hip_bf16.h>

// Problem dims (fixed)
#define BB 8
#define TT 1024
#define DD 1024
#define HH 16
#define AA 64
#define EE 262144

typedef unsigned short u16;
typedef unsigned int u32;
typedef short bf16x4 __attribute__((ext_vector_type(4)));
typedef short bf16x8 __attribute__((ext_vector_type(8)));
typedef float f32x4 __attribute__((ext_vector_type(4)));

__device__ __forceinline__ float bf2f(u16 u) {
    union { float f; u32 i; } c; c.i = ((u32)u) << 16; return c.f;
}
__device__ __forceinline__ u16 f2bf(float f) {
    union { float f; u32 i; } c; c.f = f;
    u32 x = c.i;
    return (u16)((x + 0x7FFFu + ((x >> 16) & 1u)) >> 16);
}
// packed 2xf32 -> 2xbf16 (v_cvt_pk_bf16_f32 on gfx950)
__device__ __forceinline__ u32 pack2bf(float a, float b) {
    union { __hip_bfloat162 h; u32 u; } c;
    c.h = __float22bfloat162_rn(float2{a, b});
    return c.u;
}

// async 16B global->LDS (per-lane gptr; LDS dest = wave-uniform base + lane*16)
#define GLDS16(gp, lp)                                                        \
    __builtin_amdgcn_global_load_lds(                                         \
        (const __attribute__((address_space(1))) u32*)(const void*)(gp),      \
        (__attribute__((address_space(3))) u32*)(void*)(lp), 16, 0, 0)

#define MFMA(a, b, c) __builtin_amdgcn_mfma_f32_16x16x32_bf16((a), (b), (c), 0, 0, 0)

// ---------------------------------------------------------------------------
// cvt: elementwise f32 -> bf16 (8 elems/thread), BW-bound
// ---------------------------------------------------------------------------
__global__ __launch_bounds__(256) void cvt(const float* __restrict__ src,
                                           u16* __restrict__ dst) {
    size_t i = ((size_t)blockIdx.x * 256 + threadIdx.x) * 8;
    f32x4 a = *(const f32x4*)(src + i);
    f32x4 b = *(const f32x4*)(src + i + 4);
    u32 o[4];
    o[0] = pack2bf(a[0], a[1]);
    o[1] = pack2bf(a[2], a[3]);
    o[2] = pack2bf(b[0], b[1]);
    o[3] = pack2bf(b[2], b[3]);
    *(bf16x8*)(dst + i) = *(bf16x8*)o;
}

// ---------------------------------------------------------------------------
// mb init (bf16): mb[i] = mask ? -1e30 : 0
// ---------------------------------------------------------------------------
__global__ __launch_bounds__(256) void mbinit(const float* __restrict__ masks,
                                              u16* __restrict__ mb) {
    size_t i = ((size_t)blockIdx.x * 256 + threadIdx.x) * 8;
    f32x4 a = *(const f32x4*)(masks + i);
    f32x4 b = *(const f32x4*)(masks + i + 4);
    const u16 M = f2bf(-1.0e30f);
    bf16x8 o;
#pragma unroll
    for (int j = 0; j < 4; j++) {
        o[j] = (short)((a[j] != 0.f) ? M : 0);
        o[4 + j] = (short)((b[j] != 0.f) ? M : 0);
    }
    *(bf16x8*)(mb + i) = o;
}

// ---------------------------------------------------------------------------
// scatter pass 1 — last edge index wins (numpy semantics)
// ---------------------------------------------------------------------------
__global__ __launch_bounds__(256) void scat_max(const int* __restrict__ ab,
                                                int* __restrict__ idx) {
    int e = blockIdx.x * 256 + threadIdx.x;
    const int* rec = ab + (size_t)e * 4;
    int b = rec[1], q = rec[2], k = rec[3];
    atomicMax(&idx[((((size_t)b << 10) + q) << 10) + k], e);
}

// scatter pass 2 — winner writes prescaled bf16 value (skip masked cells)
__global__ __launch_bounds__(256) void scat_res(const int* __restrict__ ab,
                                                const int* __restrict__ idx,
                                                const float* __restrict__ be,
                                                const float* __restrict__ bsc,
                                                u16* __restrict__ mb) {
    __shared__ float proj[32];
    int tid = threadIdx.x;
    if (tid < 32) {
        float s = 0.f;
        for (int a = 0; a < 64; a++) s += be[tid * 64 + a] * bsc[a];
        proj[tid] = s * 0.125f;  // fold 1/sqrt(A)
    }
    __syncthreads();
    int e = blockIdx.x * 256 + tid;
    const int* rec = ab + (size_t)e * 4;
    int et = rec[0], b = rec[1], q = rec[2], k = rec[3];
    size_t cell = ((((size_t)b << 10) + q) << 10) + k;
    if (idx[cell] == e && bf2f(mb[cell]) > -1.0e29f) mb[cell] = f2bf(proj[et]);
}

// ---------------------------------------------------------------------------
// transpose 4 f32 weight matrices (1024x1024) -> bf16 (N,K); Wq/Wk/Wv rows
// land contiguously, Wout last.
// ---------------------------------------------------------------------------
__global__ __launch_bounds__(256) void tr_w(const float* __restrict__ s0,
                                            const float* __restrict__ s1,
                                            const float* __restrict__ s2,
                                            const float* __restrict__ s3,
                                            u16* __restrict__ dstbase) {
    __shared__ u16 t[64 * 72];
    int tid = threadIdx.x;
    int z = blockIdx.z;
    const float* src = (z == 0) ? s0 : (z == 1) ? s1 : (z == 2) ? s2 : s3;
    u16* dst = dstbase + (size_t)z * 1024 * 1024;
    int row0 = blockIdx.y * 64, col0 = blockIdx.x * 64;
    int r = tid >> 2, c0 = (tid & 3) * 16;
    const float* sp = src + (size_t)(row0 + r) * 1024 + col0 + c0;
    f32x4 f0 = *(const f32x4*)(sp);
    f32x4 f1 = *(const f32x4*)(sp + 4);
    f32x4 f2_ = *(const f32x4*)(sp + 8);
    f32x4 f3 = *(const f32x4*)(sp + 12);
#pragma unroll
    for (int j = 0; j < 4; j++) {
        t[r * 72 + c0 + j] = f2bf(f0[j]);
        t[r * 72 + c0 + 4 + j] = f2bf(f1[j]);
        t[r * 72 + c0 + 8 + j] = f2bf(f2_[j]);
        t[r * 72 + c0 + 12 + j] = f2bf(f3[j]);
    }
    __syncthreads();
    bf16x8 o0, o1;
#pragma unroll
    for (int j = 0; j < 8; j++) o0[j] = (short)t[(c0 + j) * 72 + r];
#pragma unroll
    for (int j = 0; j < 8; j++) o1[j] = (short)t[(c0 + 8 + j) * 72 + r];
    *(bf16x8*)(dst + (size_t)(col0 + r) * 1024 + row0 + c0) = o0;
    *(bf16x8*)(dst + (size_t)(col0 + r) * 1024 + row0 + c0 + 8) = o1;
}

// ---------------------------------------------------------------------------
// gemm4: 128x128 tile, BK=64, both operands via global_load_lds width=16.
// XOR chunk swizzle on the GLOBAL source pointer (LDS slot is lane-linear):
// LDS[row][phys] holds global chunk phys^(row&7); frag ds_read_b128 at
// phys=(cl^(l16&7)) spreads 16 lanes over all 32 banks (2-way max = free).
// A bf16 (M,K=1024). BT bf16 (N,K). mode 0: C0 = f32 (M,1024).
// mode 1: bf16 [B,H,T,A] outputs; block's matrix = nbase>>10 selects
// C0/C1/C2; scale applies to matrix 0 only (sc0).
// ---------------------------------------------------------------------------
__global__ __launch_bounds__(256) void gemm4(const u16* __restrict__ A,
                                             const u16* __restrict__ BT,
                                             void* __restrict__ C0,
                                             void* __restrict__ C1,
                                             void* __restrict__ C2,
                                             int mode, float sc0) {
    __shared__ u16 Asm[128 * 64];
    __shared__ u16 Bsm[128 * 64];
    int tid = threadIdx.x;
    int wave = tid >> 6, lane = tid & 63;
    int quad = lane >> 4, l16 = lane & 15;
    int wm = wave >> 1, wn = wave & 1;
    int mbase = blockIdx.y * 128, nbase = blockIdx.x * 128;
    f32x4 acc[4][4] = {};
    int srow = wave * 32 + (lane >> 3);
    int schunk = (lane & 7) ^ (lane >> 3);
    const u16* gA = A + (size_t)(mbase + srow) * 1024 + schunk * 8;
    const u16* gB = BT + (size_t)(nbase + srow) * 1024 + schunk * 8;
    u16* lA = Asm + wave * 2048;
    u16* lB = Bsm + wave * 2048;
    int sx = l16 & 7;
    for (int k0 = 0; k0 < 1024; k0 += 64) {
        __syncthreads();
#pragma unroll
        for (int j = 0; j < 4; j++) GLDS16(gA + k0 + j * 8192, lA + j * 512);
#pragma unroll
        for (int j = 0; j < 4; j++) GLDS16(gB + k0 + j * 8192, lB + j * 512);
        __syncthreads();
#pragma unroll
        for (int kk = 0; kk < 2; kk++) {
            bf16x8 af[4], bfr[4];
#pragma unroll
            for (int mt = 0; mt < 4; mt++)
                af[mt] = *(const bf16x8*)&Asm[(wm * 64 + mt * 16 + l16) * 64 +
                                              ((kk * 4 + quad) ^ sx) * 8];
#pragma unroll
            for (int nt = 0; nt < 4; nt++)
                bfr[nt] = *(const bf16x8*)&Bsm[(wn * 64 + nt * 16 + l16) * 64 +
                                               ((kk * 4 + quad) ^ sx) * 8];
#pragma unroll
            for (int mt = 0; mt < 4; mt++)
#pragma unroll
                for (int nt = 0; nt < 4; nt++)
                    acc[mt][nt] = MFMA(af[mt], bfr[nt], acc[mt][nt]);
        }
    }
    if (mode == 0) {
#pragma unroll
        for (int mt = 0; mt < 4; mt++)
#pragma unroll
            for (int nt = 0; nt < 4; nt++)
#pragma unroll
                for (int r = 0; r < 4; r++) {
                    int gm = mbase + wm * 64 + mt * 16 + quad * 4 + r;
                    int gn = nbase + wn * 64 + nt * 16 + l16;
                    ((float*)C0)[(size_t)gm * 1024 + gn] = acc[mt][nt][r];
                }
    } else {
        int mat = nbase >> 10;
        int nloc = nbase & 1023;
        u16* dst = (u16*)((mat == 0) ? C0 : (mat == 1) ? C1 : C2);
        float sc = (mat == 0) ? sc0 : 1.0f;
#pragma unroll
        for (int mt = 0; mt < 4; mt++)
#pragma unroll
            for (int nt = 0; nt < 4; nt++)
#pragma unroll
                for (int r = 0; r < 4; r++) {
                    int gm = mbase + wm * 64 + mt * 16 + quad * 4 + r;
                    int gnl = nloc + wn * 64 + nt * 16 + l16;
                    int b = gm >> 10, t = gm & 1023, h = gnl >> 6, a = gnl & 63;
                    dst[(((size_t)(b * 16 + h) * 1024) + t) * 64 + a] =
                        f2bf(acc[mt][nt][r] * sc);
                }
    }
}

// ---------------------------------------------------------------------------
// transpose v [B,H,T,A] -> vT [B,H,A,T]  (bf16)
// ---------------------------------------------------------------------------
__global__ __launch_bounds__(256) void tr_v(const u16* __restrict__ v,
                                            u16* __restrict__ vT) {
    __shared__ u16 t[64 * 72];
    int tid = threadIdx.x;
    int bh = blockIdx.y;
    int t0 = blockIdx.x * 64;
    int r = tid >> 2, c0 = (tid & 3) * 16;
    const u16* src = v + (size_t)bh * 1024 * 64;
    u16* dst = vT + (size_t)bh * 64 * 1024;
    bf16x8 v0 = *(const bf16x8*)(src + (size_t)(t0 + r) * 64 + c0);
    bf16x8 v1 = *(const bf16x8*)(src + (size_t)(t0 + r) * 64 + c0 + 8);
    *(bf16x8*)&t[r * 72 + c0] = v0;
    *(bf16x8*)&t[r * 72 + c0 + 8] = v1;
    __syncthreads();
    bf16x8 o0, o1;
#pragma unroll
    for (int j = 0; j < 8; j++) o0[j] = (short)t[(c0 + j) * 72 + r];
#pragma unroll
    for (int j = 0; j < 8; j++) o1[j] = (short)t[(c0 + 8 + j) * 72 + r];
    *(bf16x8*)(dst + (size_t)r * 1024 + t0 + c0) = o0;
    *(bf16x8*)(dst + (size_t)r * 1024 + t0 + c0 + 8) = o1;
}

// ---------------------------------------------------------------------------
// ksum[b,h,t] = sum_a k[b,h,t,a]
// ---------------------------------------------------------------------------
__global__ __launch_bounds__(256) void ksumk(const u16* __restrict__ k,
                                             float* __restrict__ ks) {
    int i = blockIdx.x * 256 + threadIdx.x;
    const u16* kp = k + (size_t)i * 64;
    float s = 0.f;
#pragma unroll
    for (int c = 0; c < 64; c += 8) {
        bf16x8 v = *(const bf16x8*)(kp + c);
#pragma unroll
        for (int j = 0; j < 8; j++) s += bf2f((u16)v[j]);
    }
    ks[i] = s;
}

// ---------------------------------------------------------------------------
// attn3: q-tile 128 (4 waves x 2 stripes of 16 q-rows), K-blocks of 64.
// S^T = K.Q^T (packed P writes), fixed-offset softmax (-20), bf16 mb.
// ---------------------------------------------------------------------------
__global__ __launch_bounds__(256) void attn3(const u16* __restrict__ qbuf,
                                             const u16* __restrict__ kbuf,
                                             const u16* __restrict__ vT,
                                             const float* __restrict__ ksum,
                                             const u16* __restrict__ mb,
                                             u16* __restrict__ ctx) {
    __shared__ u16 Ksm[64 * 72];
    __shared__ u16 Vsm[64 * 72];
    __shared__ u16 Psm[4 * 16 * 72];
    __shared__ float sksm[64];
    __shared__ float lsm[128];
    int tid = threadIdx.x;
    int wave = tid >> 6, lane = tid & 63;
    int quad = lane >> 4, l16 = lane & 15;
    int qb = blockIdx.x, h = blockIdx.y, b = blockIdx.z;
    int bh = b * 16 + h;
    const u16* qp = qbuf + (size_t)bh * 65536;
    const u16* kp = kbuf + (size_t)bh * 65536;
    const u16* vp = vT + (size_t)bh * 65536;
    const float* ksp = ksum + (size_t)bh * 1024;
    int q0w = qb * 128 + wave * 32;
    const u16* mbp[2];
    bf16x8 qf[2][2];
#pragma unroll
    for (int s = 0; s < 2; s++) {
        int qs = q0w + s * 16;
        mbp[s] = mb + ((size_t)b * 1024 + qs + l16) * 1024;
        qf[s][0] = *(const bf16x8*)(qp + (size_t)(qs + l16) * 64 + quad * 8);
        qf[s][1] = *(const bf16x8*)(qp + (size_t)(qs + l16) * 64 + 32 + quad * 8);
    }

    f32x4 oacc[2][4] = {};
    float lsum[2] = {0.f, 0.f};
    int srow = tid >> 2, sc0 = (tid & 3) * 16;
    u16* pw = &Psm[wave * 16 * 72];

    for (int kb = 0; kb < 1024; kb += 64) {
        bf16x8 k0 = *(const bf16x8*)(kp + (size_t)(kb + srow) * 64 + sc0);
        bf16x8 k1 = *(const bf16x8*)(kp + (size_t)(kb + srow) * 64 + sc0 + 8);
        bf16x8 v0 = *(const bf16x8*)(vp + (size_t)srow * 1024 + kb + sc0);
        bf16x8 v1 = *(const bf16x8*)(vp + (size_t)srow * 1024 + kb + sc0 + 8);
        bf16x4 mraw[2][4];
#pragma unroll
        for (int s = 0; s < 2; s++)
#pragma unroll
            for (int nt = 0; nt < 4; nt++)
                mraw[s][nt] = *(const bf16x4*)(mbp[s] + kb + nt * 16 + quad * 4);
        __syncthreads();
        *(bf16x8*)&Ksm[srow * 72 + sc0] = k0;
        *(bf16x8*)&Ksm[srow * 72 + sc0 + 8] = k1;
        *(bf16x8*)&Vsm[srow * 72 + sc0] = v0;
        *(bf16x8*)&Vsm[srow * 72 + sc0 + 8] = v1;
        if (tid < 64) sksm[tid] = ksp[kb + tid];
        __syncthreads();

#pragma unroll
        for (int s = 0; s < 2; s++) {
            f32x4 sacc[4];
#pragma unroll
            for (int nt = 0; nt < 4; nt++) sacc[nt] = f32x4{-20.f, -20.f, -20.f, -20.f};
#pragma unroll
            for (int nt = 0; nt < 4; nt++) {
                bf16x8 kf0 = *(const bf16x8*)&Ksm[(nt * 16 + l16) * 72 + quad * 8];
                bf16x8 kf1 = *(const bf16x8*)&Ksm[(nt * 16 + l16) * 72 + 32 + quad * 8];
                sacc[nt] = MFMA(kf0, qf[s][0], sacc[nt]);
                sacc[nt] = MFMA(kf1, qf[s][1], sacc[nt]);
            }
#pragma unroll
            for (int nt = 0; nt < 4; nt++) {
                f32x4 k4 = *(const f32x4*)&sksm[nt * 16 + quad * 4];
                float p[4];
#pragma unroll
                for (int r = 0; r < 4; r++) {
                    float f = bf2f((u16)mraw[s][nt][r]);
                    float e = __expf(sacc[nt][r] + f * k4[r]);
                    p[r] = (f > -1.0e29f) ? e : 0.f;
                    lsum[s] += p[r];
                }
                *(u32*)&pw[l16 * 72 + nt * 16 + quad * 4] = pack2bf(p[0], p[1]);
                *(u32*)&pw[l16 * 72 + nt * 16 + quad * 4 + 2] = pack2bf(p[2], p[3]);
            }
#pragma unroll
            for (int hs = 0; hs < 2; hs++) {
                bf16x8 pf = *(const bf16x8*)&pw[l16 * 72 + hs * 32 + quad * 8];
#pragma unroll
                for (int at = 0; at < 4; at++) {
                    bf16x8 vf = *(const bf16x8*)&Vsm[(at * 16 + l16) * 72 + hs * 32 + quad * 8];
                    oacc[s][at] = MFMA(pf, vf, oacc[s][at]);
                }
            }
        }
    }

#pragma unroll
    for (int s = 0; s < 2; s++) {
        lsum[s] += __shfl_xor(lsum[s], 16);
        lsum[s] += __shfl_xor(lsum[s], 32);
        if (lane < 16) lsm[wave * 32 + s * 16 + lane] = lsum[s];
    }
    __syncthreads();

#pragma unroll
    for (int s = 0; s < 2; s++)
#pragma unroll
        for (int r = 0; r < 4; r++) {
            float linv = 1.0f / lsm[wave * 32 + s * 16 + quad * 4 + r];
            int q = q0w + s * 16 + quad * 4 + r;
#pragma unroll
            for (int at = 0; at < 4; at++) {
                ctx[(((size_t)b * 1024 + q) * 16 + h) * 64 + at * 16 + l16] =
                    f2bf(oacc[s][at][r] * linv);
            }
        }
}

// ---------------------------------------------------------------------------
extern "C" void kernel_launch(void* const* d_in, const int* in_sizes, int n_in,
                              void* d_out, int out_size, void* d_ws, size_t ws_size,
                              hipStream_t stream) {
    const float* states = (const float*)d_in[0];
    const float* key_states = (const float*)d_in[1];
    const float* masks = (const float*)d_in[2];
    const int* abias = (const int*)d_in[3];
    const float* Wq = (const float*)d_in[4];
    const float* Wk = (const float*)d_in[5];
    const float* Wv = (const float*)d_in[6];
    const float* Wout = (const float*)d_in[7];
    const float* be = (const float*)d_in[8];
    const float* bsc = (const float*)d_in[9];

    char* ws = (char*)d_ws;
    size_t off = 0;
    auto alloc = [&](size_t n) { void* p = ws + off; off += (n + 255) & ~(size_t)255; return p; };
    u16* wT = (u16*)alloc(4ull * 1024 * 1024 * 2);          // [Wq|Wk|Wv|Wout]^T bf16 (8 MB)
    u16* sbf = (u16*)alloc((size_t)BB * TT * DD * 2);       // states bf16 (16 MB)
    u16* kbf = (u16*)alloc((size_t)BB * TT * DD * 2);       // key_states bf16 (16 MB)
    u16* qb_ = (u16*)alloc((size_t)BB * HH * TT * AA * 2);  // q [B,H,T,A] (16 MB)
    u16* kb_ = (u16*)alloc((size_t)BB * HH * TT * AA * 2);  // k [B,H,T,A] (16 MB)
    u16* vb_ = (u16*)alloc((size_t)BB * HH * TT * AA * 2);  // v [B,H,T,A] (16 MB)
    u16* vT_ = (u16*)alloc((size_t)BB * HH * AA * TT * 2);  // vT [B,H,A,T] (16 MB)
    float* ks_ = (float*)alloc((size_t)BB * HH * TT * 4);   // ksum (0.5 MB)
    u16* mb_ = (u16*)alloc((size_t)BB * TT * TT * 2);       // fused mask+bias bf16 (16 MB)

    u16* wqT = wT;                  // (1024,1024)
    u16* wkvT = wT + 1048576;       // (2048,1024) contiguous Wk|Wv
    u16* woT = wT + 3145728;
    int* idx_ = (int*)qb_;   // 32 MB over qb_+kb_ (dead until projections)
    u16* ctx_ = vb_;         // vb_ dead after tr_v

    // 1) scatter-idx init + fused mask/bias init (bf16)
    hipMemsetAsync(idx_, 0xFF, (size_t)BB * TT * TT * 4, stream);
    mbinit<<<dim3(4096), 256, 0, stream>>>(masks, mb_);
    // 2) deterministic scatter (last-edge-wins, masked cells excluded)
    scat_max<<<dim3(EE / 256), 256, 0, stream>>>(abias, idx_);
    scat_res<<<dim3(EE / 256), 256, 0, stream>>>(abias, idx_, be, bsc, mb_);
    // 3) weights f32 -> bf16 transposed
    tr_w<<<dim3(16, 16, 4), 256, 0, stream>>>(Wq, Wk, Wv, Wout, wT);
    // 4) activations f32 -> bf16
    cvt<<<dim3(4096), 256, 0, stream>>>(states, sbf);
    cvt<<<dim3(4096), 256, 0, stream>>>(key_states, kbf);
    // 5) projections: Q (scaled 0.125), fused K|V (N=2048)
    gemm4<<<dim3(8, 64), 256, 0, stream>>>(sbf, wqT, qb_, nullptr, nullptr, 1, 0.125f);
    gemm4<<<dim3(16, 64), 256, 0, stream>>>(kbf, wkvT, kb_, vb_, nullptr, 1, 1.0f);
    // 6) v transpose
    tr_v<<<dim3(16, 128), 256, 0, stream>>>(vb_, vT_);
    // 7) ksum
    ksumk<<<dim3(512), 256, 0, stream>>>(kb_, ks_);
    // 8) attention (q-tile 128, bf16 mb)
    attn3<<<dim3(8, 16, 8), 256, 0, stream>>>(qb_, kb_, vT_, ks_, mb_, ctx_);
    // 9) output projection -> d_out (f32)
    gemm4<<<dim3(8, 64), 256, 0, stream>>>(ctx_, woT, d_out, nullptr, nullptr, 0, 1.0f);
}

// Round 7
// 371.610 us; speedup vs baseline: 1.3252x; 1.1057x over previous
//
#include <hip/hip_runtime.h>
#include <hip/hip_bf16.h>

// Problem dims (fixed)
#define BB 8
#define TT 1024
#define DD 1024
#define HH 16
#define AA 64
#define EE 262144

typedef unsigned short u16;
typedef unsigned int u32;
typedef short bf16x4 __attribute__((ext_vector_type(4)));
typedef short bf16x8 __attribute__((ext_vector_type(8)));
typedef float f32x4 __attribute__((ext_vector_type(4)));

__device__ __forceinline__ float bf2f(u16 u) {
    union { float f; u32 i; } c; c.i = ((u32)u) << 16; return c.f;
}
__device__ __forceinline__ u16 f2bf(float f) {
    union { float f; u32 i; } c; c.f = f;
    u32 x = c.i;
    return (u16)((x + 0x7FFFu + ((x >> 16) & 1u)) >> 16);
}
// packed 2xf32 -> 2xbf16 (v_cvt_pk_bf16_f32 on gfx950)
__device__ __forceinline__ u32 pack2bf(float a, float b) {
    union { __hip_bfloat162 h; u32 u; } c;
    c.h = __float22bfloat162_rn(float2{a, b});
    return c.u;
}

// async 16B global->LDS (per-lane gptr; LDS dest = wave-uniform base + lane*16)
#define GLDS16(gp, lp)                                                        \
    __builtin_amdgcn_global_load_lds(                                         \
        (const __attribute__((address_space(1))) u32*)(const void*)(gp),      \
        (__attribute__((address_space(3))) u32*)(void*)(lp), 16, 0, 0)

#define MFMA(a, b, c) __builtin_amdgcn_mfma_f32_16x16x32_bf16((a), (b), (c), 0, 0, 0)

// ---------------------------------------------------------------------------
// prep1: fused independent prep work, partitioned by blockIdx.x
//  [0,4096)      cvt states -> sbf
//  [4096,8192)   cvt key_states -> kbf
//  [8192,12288)  mbinit (masks -> bf16 mb)
//  [12288,16384) idx init (-1)
//  [16384,17408) tr_w (4x 1024x1024 f32 -> bf16 transposed)
// ---------------------------------------------------------------------------
__global__ __launch_bounds__(256) void prep1(const float* __restrict__ states,
                                             const float* __restrict__ keys,
                                             const float* __restrict__ masks,
                                             const float* __restrict__ Wq,
                                             const float* __restrict__ Wk,
                                             const float* __restrict__ Wv,
                                             const float* __restrict__ Wout,
                                             u16* __restrict__ sbf,
                                             u16* __restrict__ kbf,
                                             u16* __restrict__ mb,
                                             int* __restrict__ idx,
                                             u16* __restrict__ wT) {
    __shared__ u16 t[64 * 72];
    int bi = blockIdx.x, tid = threadIdx.x;
    if (bi < 12288) {
        if (bi < 8192) {  // cvt
            const float* src = (bi < 4096) ? states : keys;
            u16* dst = (bi < 4096) ? sbf : kbf;
            size_t i = ((size_t)(bi & 4095) * 256 + tid) * 8;
            f32x4 a = *(const f32x4*)(src + i);
            f32x4 b = *(const f32x4*)(src + i + 4);
            u32 o[4];
            o[0] = pack2bf(a[0], a[1]);
            o[1] = pack2bf(a[2], a[3]);
            o[2] = pack2bf(b[0], b[1]);
            o[3] = pack2bf(b[2], b[3]);
            *(bf16x8*)(dst + i) = *(bf16x8*)o;
        } else {  // mbinit
            size_t i = ((size_t)(bi - 8192) * 256 + tid) * 8;
            f32x4 a = *(const f32x4*)(masks + i);
            f32x4 b = *(const f32x4*)(masks + i + 4);
            const u16 M = f2bf(-1.0e30f);
            bf16x8 o;
#pragma unroll
            for (int j = 0; j < 4; j++) {
                o[j] = (short)((a[j] != 0.f) ? M : 0);
                o[4 + j] = (short)((b[j] != 0.f) ? M : 0);
            }
            *(bf16x8*)(mb + i) = o;
        }
    } else if (bi < 16384) {  // idx init
        size_t i = ((size_t)(bi - 12288) * 256 + tid) * 8;
        int4 m1 = {-1, -1, -1, -1};
        *(int4*)(idx + i) = m1;
        *(int4*)(idx + i + 4) = m1;
    } else {  // tr_w
        int zb = bi - 16384;
        int z = zb >> 8, by = (zb >> 4) & 15, bx = zb & 15;
        const float* src = (z == 0) ? Wq : (z == 1) ? Wk : (z == 2) ? Wv : Wout;
        u16* dst = wT + (size_t)z * 1048576;
        int row0 = by * 64, col0 = bx * 64;
        int r = tid >> 2, c0 = (tid & 3) * 16;
        const float* sp = src + (size_t)(row0 + r) * 1024 + col0 + c0;
        f32x4 f0 = *(const f32x4*)(sp);
        f32x4 f1 = *(const f32x4*)(sp + 4);
        f32x4 f2_ = *(const f32x4*)(sp + 8);
        f32x4 f3 = *(const f32x4*)(sp + 12);
#pragma unroll
        for (int j = 0; j < 4; j++) {
            t[r * 72 + c0 + j] = f2bf(f0[j]);
            t[r * 72 + c0 + 4 + j] = f2bf(f1[j]);
            t[r * 72 + c0 + 8 + j] = f2bf(f2_[j]);
            t[r * 72 + c0 + 12 + j] = f2bf(f3[j]);
        }
        __syncthreads();
        bf16x8 o0, o1;
#pragma unroll
        for (int j = 0; j < 8; j++) o0[j] = (short)t[(c0 + j) * 72 + r];
#pragma unroll
        for (int j = 0; j < 8; j++) o1[j] = (short)t[(c0 + 8 + j) * 72 + r];
        *(bf16x8*)(dst + (size_t)(col0 + r) * 1024 + row0 + c0) = o0;
        *(bf16x8*)(dst + (size_t)(col0 + r) * 1024 + row0 + c0 + 8) = o1;
    }
}

// ---------------------------------------------------------------------------
// scatter pass 1 — last edge index wins (numpy semantics)
// ---------------------------------------------------------------------------
__global__ __launch_bounds__(256) void scat_max(const int* __restrict__ ab,
                                                int* __restrict__ idx) {
    int e = blockIdx.x * 256 + threadIdx.x;
    int4 rec = ((const int4*)ab)[e];
    atomicMax(&idx[((((size_t)rec.y << 10) + rec.z) << 10) + rec.w], e);
}

// scatter pass 2 — winner writes prescaled bf16 value (skip masked cells)
__global__ __launch_bounds__(256) void scat_res(const int* __restrict__ ab,
                                                const int* __restrict__ idx,
                                                const float* __restrict__ be,
                                                const float* __restrict__ bsc,
                                                u16* __restrict__ mb) {
    __shared__ float proj[32];
    int tid = threadIdx.x;
    if (tid < 32) {
        float s = 0.f;
        for (int a = 0; a < 64; a++) s += be[tid * 64 + a] * bsc[a];
        proj[tid] = s * 0.125f;  // fold 1/sqrt(A)
    }
    __syncthreads();
    int e = blockIdx.x * 256 + tid;
    int4 rec = ((const int4*)ab)[e];
    size_t cell = ((((size_t)rec.y << 10) + rec.z) << 10) + rec.w;
    if (idx[cell] == e && bf2f(mb[cell]) > -1.0e29f) mb[cell] = f2bf(proj[rec.x]);
}

// ---------------------------------------------------------------------------
// gemm5: fused QKV projection. grid (24,64): mat = x>>3 (0=Q,1=K,2=V).
// 128x128 tile, BK=64, both operands via global_load_lds w/ global-side XOR
// chunk swizzle (conflict-free unpadded LDS reads).
// mat 0: qb [B,H,T,A] bf16, scaled 0.125.
// mat 1: kb [B,H,T,A] bf16 + ksum f32 (shuffle-reduced in epilogue).
// mat 2: vT [B,H,A,T] bf16 via LDS transpose epilogue.
// ---------------------------------------------------------------------------
__global__ __launch_bounds__(256) void gemm5(const u16* __restrict__ sbf,
                                             const u16* __restrict__ kbf,
                                             const u16* __restrict__ wT,
                                             u16* __restrict__ qb,
                                             u16* __restrict__ kb,
                                             u16* __restrict__ vT,
                                             float* __restrict__ ks) {
    __shared__ u16 smem[17408];  // 34816 B: staging [0,16384) u16, transpose 128x136
    int tid = threadIdx.x;
    int wave = tid >> 6, lane = tid & 63;
    int quad = lane >> 4, l16 = lane & 15;
    int wm = wave >> 1, wn = wave & 1;
    int mat = blockIdx.x >> 3;
    int nloc = (blockIdx.x & 7) * 128;
    int mbase = blockIdx.y * 128;
    const u16* A = (mat == 0) ? sbf : kbf;
    const u16* BT = wT + (size_t)mat * 1048576;
    u16* Asm = smem;
    u16* Bsm = smem + 8192;
    f32x4 acc[4][4] = {};
    int srow = wave * 32 + (lane >> 3);
    int schunk = (lane & 7) ^ (lane >> 3);
    const u16* gA = A + (size_t)(mbase + srow) * 1024 + schunk * 8;
    const u16* gB = BT + (size_t)(nloc + srow) * 1024 + schunk * 8;
    u16* lA = Asm + wave * 2048;
    u16* lB = Bsm + wave * 2048;
    int sx = l16 & 7;
    for (int k0 = 0; k0 < 1024; k0 += 64) {
        __syncthreads();
#pragma unroll
        for (int j = 0; j < 4; j++) GLDS16(gA + k0 + j * 8192, lA + j * 512);
#pragma unroll
        for (int j = 0; j < 4; j++) GLDS16(gB + k0 + j * 8192, lB + j * 512);
        __syncthreads();
#pragma unroll
        for (int kk = 0; kk < 2; kk++) {
            bf16x8 af[4], bfr[4];
#pragma unroll
            for (int mt = 0; mt < 4; mt++)
                af[mt] = *(const bf16x8*)&Asm[(wm * 64 + mt * 16 + l16) * 64 +
                                              ((kk * 4 + quad) ^ sx) * 8];
#pragma unroll
            for (int nt = 0; nt < 4; nt++)
                bfr[nt] = *(const bf16x8*)&Bsm[(wn * 64 + nt * 16 + l16) * 64 +
                                               ((kk * 4 + quad) ^ sx) * 8];
#pragma unroll
            for (int mt = 0; mt < 4; mt++)
#pragma unroll
                for (int nt = 0; nt < 4; nt++)
                    acc[mt][nt] = MFMA(af[mt], bfr[nt], acc[mt][nt]);
        }
    }

    if (mat == 2) {
        // V: transpose through LDS -> vT [B,H,A,T]
        __syncthreads();  // all waves done with staging LDS
#pragma unroll
        for (int mt = 0; mt < 4; mt++)
#pragma unroll
            for (int nt = 0; nt < 4; nt++)
#pragma unroll
                for (int r = 0; r < 4; r++) {
                    int rowl = wm * 64 + mt * 16 + quad * 4 + r;
                    int coll = wn * 64 + nt * 16 + l16;
                    smem[coll * 136 + rowl] = f2bf(acc[mt][nt][r]);
                }
        __syncthreads();
        int b = mbase >> 10, t0 = mbase & 1023;
        int c = tid >> 1, hf = tid & 1;
        int h = (nloc >> 6) + (c >> 6);
        int a = c & 63;
        u16* dst = vT + ((((size_t)(b * 16 + h)) * 64 + a) << 10) + t0 + hf * 64;
        const u16* srcl = smem + c * 136 + hf * 64;
#pragma unroll
        for (int j = 0; j < 8; j++) *(bf16x8*)(dst + j * 8) = *(const bf16x8*)(srcl + j * 8);
    } else {
        u16* dst = (mat == 0) ? qb : kb;
        float sc = (mat == 0) ? 0.125f : 1.0f;
#pragma unroll
        for (int mt = 0; mt < 4; mt++)
#pragma unroll
            for (int nt = 0; nt < 4; nt++)
#pragma unroll
                for (int r = 0; r < 4; r++) {
                    int gm = mbase + wm * 64 + mt * 16 + quad * 4 + r;
                    int gnl = nloc + wn * 64 + nt * 16 + l16;
                    int b = gm >> 10, t = gm & 1023, h = gnl >> 6, a = gnl & 63;
                    dst[(((size_t)(b * 16 + h) * 1024) + t) * 64 + a] =
                        f2bf(acc[mt][nt][r] * sc);
                }
        if (mat == 1) {
            // ksum[b,h,t] = sum_a K (f32 acc, pre-rounding)
            int h = (nloc + wn * 64) >> 6;
#pragma unroll
            for (int mt = 0; mt < 4; mt++)
#pragma unroll
                for (int r = 0; r < 4; r++) {
                    float s = acc[mt][0][r] + acc[mt][1][r] + acc[mt][2][r] + acc[mt][3][r];
                    s += __shfl_xor(s, 1);
                    s += __shfl_xor(s, 2);
                    s += __shfl_xor(s, 4);
                    s += __shfl_xor(s, 8);
                    if (l16 == 0) {
                        int gm = mbase + wm * 64 + mt * 16 + quad * 4 + r;
                        int b = gm >> 10, t = gm & 1023;
                        ks[(((size_t)(b * 16 + h)) << 10) + t] = s;
                    }
                }
        }
    }
}

// ---------------------------------------------------------------------------
// attn4: 64-q tile (wave = 16 q-rows), K-blocks of 64. K/V staged via
// global_load_lds with XOR chunk swizzle (unpadded 64-u16 rows). S^T = K.Q^T,
// fixed-offset softmax (-20), bf16 mb, packed P writes to padded Psm.
// ---------------------------------------------------------------------------
__global__ __launch_bounds__(256) void attn4(const u16* __restrict__ qbuf,
                                             const u16* __restrict__ kbuf,
                                             const u16* __restrict__ vT,
                                             const float* __restrict__ ksum,
                                             const u16* __restrict__ mb,
                                             u16* __restrict__ ctx) {
    __shared__ u16 Ksm[64 * 64];
    __shared__ u16 Vsm[64 * 64];
    __shared__ u16 Psm[4 * 16 * 72];
    __shared__ float sksm[64];
    __shared__ float lsm[64];
    int tid = threadIdx.x;
    int wave = tid >> 6, lane = tid & 63;
    int quad = lane >> 4, l16 = lane & 15;
    int qb = blockIdx.x, h = blockIdx.y, b = blockIdx.z;
    int bh = b * 16 + h;
    const u16* qp = qbuf + (size_t)bh * 65536;
    const u16* kp = kbuf + (size_t)bh * 65536;
    const u16* vp = vT + (size_t)bh * 65536;
    const float* ksp = ksum + (size_t)bh * 1024;
    int q0 = qb * 64 + wave * 16;
    const u16* mbp = mb + ((size_t)b * 1024 + q0 + l16) * 1024;

    bf16x8 qf0 = *(const bf16x8*)(qp + (size_t)(q0 + l16) * 64 + quad * 8);
    bf16x8 qf1 = *(const bf16x8*)(qp + (size_t)(q0 + l16) * 64 + 32 + quad * 8);

    f32x4 oacc[4] = {};
    float lsum = 0.f;
    // staging geometry: lane -> row octet (lane>>3), swizzled chunk
    int r8 = lane >> 3;
    int sch = (lane & 7) ^ r8;
    u16* lK = Ksm + wave * 1024;
    u16* lV = Vsm + wave * 1024;
    const u16* gK0 = kp + (size_t)(wave * 16 + r8) * 64 + sch * 8;
    const u16* gV0 = vp + (size_t)(wave * 16 + r8) * 1024 + sch * 8;
    int sx = l16 & 7;
    u16* pw = &Psm[wave * 16 * 72];

    for (int kb = 0; kb < 1024; kb += 64) {
        bf16x4 mraw[4];
#pragma unroll
        for (int nt = 0; nt < 4; nt++)
            mraw[nt] = *(const bf16x4*)(mbp + kb + nt * 16 + quad * 4);
        __syncthreads();  // prev-iter LDS reads done
        GLDS16(gK0 + (size_t)kb * 64, lK);
        GLDS16(gK0 + (size_t)(kb + 8) * 64, lK + 512);
        GLDS16(gV0 + kb, lV);
        GLDS16(gV0 + 8 * 1024 + kb, lV + 512);
        if (tid < 64) sksm[tid] = ksp[kb + tid];
        __syncthreads();  // staging visible

        // S^T = K.Q^T, accumulator pre-biased with softmax offset -20
        f32x4 sacc[4];
#pragma unroll
        for (int nt = 0; nt < 4; nt++) sacc[nt] = f32x4{-20.f, -20.f, -20.f, -20.f};
#pragma unroll
        for (int nt = 0; nt < 4; nt++) {
            bf16x8 kf0 = *(const bf16x8*)&Ksm[(nt * 16 + l16) * 64 + (quad ^ sx) * 8];
            bf16x8 kf1 = *(const bf16x8*)&Ksm[(nt * 16 + l16) * 64 + ((4 + quad) ^ sx) * 8];
            sacc[nt] = MFMA(kf0, qf0, sacc[nt]);
            sacc[nt] = MFMA(kf1, qf1, sacc[nt]);
        }

        // p = unmasked ? exp(s + bias*ksum - 20) : 0 ; packed bf16 P write
#pragma unroll
        for (int nt = 0; nt < 4; nt++) {
            f32x4 k4 = *(const f32x4*)&sksm[nt * 16 + quad * 4];
            float p[4];
#pragma unroll
            for (int r = 0; r < 4; r++) {
                float f = bf2f((u16)mraw[nt][r]);
                float e = __expf(sacc[nt][r] + f * k4[r]);
                p[r] = (f > -1.0e29f) ? e : 0.f;
                lsum += p[r];
            }
            *(u32*)&pw[l16 * 72 + nt * 16 + quad * 4] = pack2bf(p[0], p[1]);
            *(u32*)&pw[l16 * 72 + nt * 16 + quad * 4 + 2] = pack2bf(p[2], p[3]);
        }

        // PV: O += P.V  (wave-private Psm round trip; DS ops in-order)
#pragma unroll
        for (int hs = 0; hs < 2; hs++) {
            bf16x8 pf = *(const bf16x8*)&pw[l16 * 72 + hs * 32 + quad * 8];
#pragma unroll
            for (int at = 0; at < 4; at++) {
                bf16x8 vf = *(const bf16x8*)&Vsm[(at * 16 + l16) * 64 +
                                                 ((hs * 4 + quad) ^ sx) * 8];
                oacc[at] = MFMA(pf, vf, oacc[at]);
            }
        }
    }

    lsum += __shfl_xor(lsum, 16);
    lsum += __shfl_xor(lsum, 32);
    if (lane < 16) lsm[wave * 16 + lane] = lsum;
    __syncthreads();

#pragma unroll
    for (int r = 0; r < 4; r++) {
        float linv = 1.0f / lsm[wave * 16 + quad * 4 + r];
        int q = q0 + quad * 4 + r;
#pragma unroll
        for (int at = 0; at < 4; at++) {
            ctx[(((size_t)b * 1024 + q) * 16 + h) * 64 + at * 16 + l16] =
                f2bf(oacc[at][r] * linv);
        }
    }
}

// ---------------------------------------------------------------------------
// gemmo: output projection, M=8192 N=1024 K=1024, f32 C. Same staging as gemm5.
// ---------------------------------------------------------------------------
__global__ __launch_bounds__(256) void gemmo(const u16* __restrict__ A,
                                             const u16* __restrict__ BT,
                                             float* __restrict__ C) {
    __shared__ u16 Asm[128 * 64];
    __shared__ u16 Bsm[128 * 64];
    int tid = threadIdx.x;
    int wave = tid >> 6, lane = tid & 63;
    int quad = lane >> 4, l16 = lane & 15;
    int wm = wave >> 1, wn = wave & 1;
    int mbase = blockIdx.y * 128, nbase = blockIdx.x * 128;
    f32x4 acc[4][4] = {};
    int srow = wave * 32 + (lane >> 3);
    int schunk = (lane & 7) ^ (lane >> 3);
    const u16* gA = A + (size_t)(mbase + srow) * 1024 + schunk * 8;
    const u16* gB = BT + (size_t)(nbase + srow) * 1024 + schunk * 8;
    u16* lA = Asm + wave * 2048;
    u16* lB = Bsm + wave * 2048;
    int sx = l16 & 7;
    for (int k0 = 0; k0 < 1024; k0 += 64) {
        __syncthreads();
#pragma unroll
        for (int j = 0; j < 4; j++) GLDS16(gA + k0 + j * 8192, lA + j * 512);
#pragma unroll
        for (int j = 0; j < 4; j++) GLDS16(gB + k0 + j * 8192, lB + j * 512);
        __syncthreads();
#pragma unroll
        for (int kk = 0; kk < 2; kk++) {
            bf16x8 af[4], bfr[4];
#pragma unroll
            for (int mt = 0; mt < 4; mt++)
                af[mt] = *(const bf16x8*)&Asm[(wm * 64 + mt * 16 + l16) * 64 +
                                              ((kk * 4 + quad) ^ sx) * 8];
#pragma unroll
            for (int nt = 0; nt < 4; nt++)
                bfr[nt] = *(const bf16x8*)&Bsm[(wn * 64 + nt * 16 + l16) * 64 +
                                               ((kk * 4 + quad) ^ sx) * 8];
#pragma unroll
            for (int mt = 0; mt < 4; mt++)
#pragma unroll
                for (int nt = 0; nt < 4; nt++)
                    acc[mt][nt] = MFMA(af[mt], bfr[nt], acc[mt][nt]);
        }
    }
#pragma unroll
    for (int mt = 0; mt < 4; mt++)
#pragma unroll
        for (int nt = 0; nt < 4; nt++)
#pragma unroll
            for (int r = 0; r < 4; r++) {
                int gm = mbase + wm * 64 + mt * 16 + quad * 4 + r;
                int gn = nbase + wn * 64 + nt * 16 + l16;
                C[(size_t)gm * 1024 + gn] = acc[mt][nt][r];
            }
}

// ---------------------------------------------------------------------------
extern "C" void kernel_launch(void* const* d_in, const int* in_sizes, int n_in,
                              void* d_out, int out_size, void* d_ws, size_t ws_size,
                              hipStream_t stream) {
    const float* states = (const float*)d_in[0];
    const float* key_states = (const float*)d_in[1];
    const float* masks = (const float*)d_in[2];
    const int* abias = (const int*)d_in[3];
    const float* Wq = (const float*)d_in[4];
    const float* Wk = (const float*)d_in[5];
    const float* Wv = (const float*)d_in[6];
    const float* Wout = (const float*)d_in[7];
    const float* be = (const float*)d_in[8];
    const float* bsc = (const float*)d_in[9];

    char* ws = (char*)d_ws;
    size_t off = 0;
    auto alloc = [&](size_t n) { void* p = ws + off; off += (n + 255) & ~(size_t)255; return p; };
    u16* wT = (u16*)alloc(4ull * 1024 * 1024 * 2);          // [Wq|Wk|Wv|Wout]^T bf16 (8 MB)
    u16* sbf = (u16*)alloc((size_t)BB * TT * DD * 2);       // states bf16 (16 MB)
    u16* kbf = (u16*)alloc((size_t)BB * TT * DD * 2);       // key_states bf16 (16 MB)
    u16* qb_ = (u16*)alloc((size_t)BB * HH * TT * AA * 2);  // q [B,H,T,A] (16 MB)
    u16* kb_ = (u16*)alloc((size_t)BB * HH * TT * AA * 2);  // k [B,H,T,A] (16 MB)
    u16* vT_ = (u16*)alloc((size_t)BB * HH * AA * TT * 2);  // vT [B,H,A,T] (16 MB)
    float* ks_ = (float*)alloc((size_t)BB * HH * TT * 4);   // ksum (0.5 MB)
    u16* mb_ = (u16*)alloc((size_t)BB * TT * TT * 2);       // fused mask+bias bf16 (16 MB)

    u16* woT = wT + 3145728;
    int* idx_ = (int*)qb_;   // 32 MB over qb_+kb_ (contiguous, dead until gemm5)
    u16* ctx_ = sbf;         // sbf dead after Q projection

    // 1) fused prep: cvt x2 + mbinit + idx init + tr_w  (all independent)
    prep1<<<dim3(17408), 256, 0, stream>>>(states, key_states, masks, Wq, Wk, Wv,
                                           Wout, sbf, kbf, mb_, idx_, wT);
    // 2) deterministic scatter (last-edge-wins, masked cells excluded)
    scat_max<<<dim3(EE / 256), 256, 0, stream>>>(abias, idx_);
    scat_res<<<dim3(EE / 256), 256, 0, stream>>>(abias, idx_, be, bsc, mb_);
    // 3) fused QKV projection (+ksum epilogue, +V-transpose epilogue)
    gemm5<<<dim3(24, 64), 256, 0, stream>>>(sbf, kbf, wT, qb_, kb_, vT_, ks_);
    // 4) attention (64-q tile, async K/V staging)
    attn4<<<dim3(16, 16, 8), 256, 0, stream>>>(qb_, kb_, vT_, ks_, mb_, ctx_);
    // 5) output projection -> d_out (f32)
    gemmo<<<dim3(8, 64), 256, 0, stream>>>(ctx_, woT, (float*)d_out);
}